// Round 13
// baseline (692.679 us; speedup 1.0000x reference)
//
#include <hip/hip_runtime.h>
#include <hip/hip_fp16.h>

#define IN_CH 11
#define HID 64
#define PAD 64
#define OVCAP 16384
#define NBLK 512
#define BSH 10           // super-bucket = dst >> 10 (1024 nodes)

typedef _Float16 half8_t __attribute__((ext_vector_type(8)));
typedef float f32x4_t __attribute__((ext_vector_type(4)));

// ---- fused prep + hist: role-split by blockIdx ----
// blocks [0,NBLK): per-chunk LDS histogram of dst>>BSH
// blocks [NBLK,..): x -> fp16 padded copy (stride 16, row N = 0), weights->fp16
__global__ __launch_bounds__(256) void k_prephist(
        const float* __restrict__ x, const float* __restrict__ Wl2,
        const float* __restrict__ Wr2, const int* __restrict__ dst,
        unsigned* __restrict__ xphu, __half* __restrict__ wl2h,
        __half* __restrict__ wr2h, int* __restrict__ hist,
        int* __restrict__ ovcnt, int E, int csz, int nbkt, int N) {
    __shared__ int h[128];
    int tid = threadIdx.x;
    if (blockIdx.x < NBLK) {
        int blk = blockIdx.x;
        if (tid < 128) h[tid] = 0;
        __syncthreads();
        int c0 = blk * csz, c1 = min(c0 + csz, E);
        for (int e = c0 + tid; e < c1; e += 256)
            atomicAdd(&h[dst[e] >> BSH], 1);
        __syncthreads();
        if (tid < nbkt) hist[tid * NBLK + blk] = h[tid];
    } else {
        int i = (blockIdx.x - NBLK) * 256 + tid;
        if (i == 0) *ovcnt = 0;
        if (i < HID * HID) {
            wl2h[i] = __float2half_rn(Wl2[i]);
            wr2h[i] = __float2half_rn(Wr2[i]);
        }
        if (i < (N + 1) * 8) {               // one uint = 2 fp16 channels
            int n = i >> 3, j = (i & 7) * 2;
            float a = 0.f, b = 0.f;
            if (n < N) {
                if (j < IN_CH) a = x[n * IN_CH + j];
                if (j + 1 < IN_CH) b = x[n * IN_CH + j + 1];
            }
            unsigned lo = (unsigned)__half_as_ushort(__float2half_rn(a));
            unsigned hi = (unsigned)__half_as_ushort(__float2half_rn(b));
            xphu[i] = lo | (hi << 16);
        }
    }
}

// per-bucket exclusive scan of its NBLK chunk counts (in place) + bucket total
__global__ __launch_bounds__(512) void k_scanA(int* __restrict__ hist,
        int* __restrict__ btot) {
    __shared__ int wsum[8];
    int b = blockIdx.x, tid = threadIdx.x;
    int lane = tid & 63, wv = tid >> 6;
    int v = hist[b * NBLK + tid];
    int inc = v;
    #pragma unroll
    for (int off = 1; off < 64; off <<= 1) {
        int t = __shfl_up(inc, off);
        if (lane >= off) inc += t;
    }
    if (lane == 63) wsum[wv] = inc;
    __syncthreads();
    int base = 0;
    #pragma unroll
    for (int w = 0; w < 8; w++) base += (w < wv) ? wsum[w] : 0;
    hist[b * NBLK + tid] = base + inc - v;
    if (tid == NBLK - 1) btot[b] = base + inc;
}

// scatter packed (dlocal<<17|src) into bucket-grouped ebuf via LDS cursors;
// bstart computed inline by a 2-wave shuffle scan of btot (nbkt <= 128)
__global__ __launch_bounds__(256) void k_scatter(const int* __restrict__ src,
        const int* __restrict__ dst, const int* __restrict__ hist,
        const int* __restrict__ btot,
        unsigned* __restrict__ ebuf, int E, int csz, int nbkt) {
    __shared__ int cur[128];
    __shared__ int wtmp;
    int tid = threadIdx.x, blk = blockIdx.x;
    int v = 0, inc = 0;
    if (tid < 128) {
        int lane = tid & 63;
        v = (tid < nbkt) ? btot[tid] : 0;
        inc = v;
        #pragma unroll
        for (int off = 1; off < 64; off <<= 1) {
            int t = __shfl_up(inc, off);
            if (lane >= off) inc += t;
        }
        if (tid == 63) wtmp = inc;
    }
    __syncthreads();
    if (tid < 128) {
        int base = (tid >= 64) ? wtmp : 0;
        int bs = base + inc - v;            // exclusive bstart[tid]
        cur[tid] = ((tid < nbkt) ? hist[tid * NBLK + blk] : 0) + bs;
    }
    __syncthreads();
    int c0 = blk * csz, c1 = min(c0 + csz, E);
    for (int e = c0 + tid; e < c1; e += 256) {
        int d = dst[e], s = src[e];
        int slot = atomicAdd(&cur[d >> BSH], 1);
        ebuf[slot] = ((unsigned)(d & 1023) << 17) | (unsigned)s;
    }
}

// one block per super-bucket: read its contiguous edges ONCE; rank via LDS;
// write col64 directly (own 256 KB L2-resident region); FUSED layer-1
// aggregation: gather xph row (L2-resident 3.2 MB table) and accumulate
// ch 0..10 into stride-17 fp32 LDS; exact over ALL edges (incl. overflow).
__global__ __launch_bounds__(1024) void k_bbuild(const unsigned* __restrict__ ebuf,
        const int* __restrict__ btot, const unsigned* __restrict__ xphu,
        int* __restrict__ cnt, int* __restrict__ col64, float* __restrict__ agg1,
        int* __restrict__ ovcnt, int* __restrict__ ov, int N) {
    __shared__ float ash[1024 * 17];    // 68 KB, stride 17 breaks bank aliasing
    __shared__ int lc[1024];
    __shared__ int sbase;
    int tid = threadIdx.x, b = blockIdx.x;
    int lo = b << BSH;
    lc[tid] = 0;
    #pragma unroll
    for (int j = 0; j < 17; j++) ash[tid + j * 1024] = 0.f;
    if (tid < 64) {                     // bstart[b] = sum btot[0..b-1]
        int s = 0;
        for (int t = tid; t < b; t += 64) s += btot[t];
        #pragma unroll
        for (int off = 32; off >= 1; off >>= 1) s += __shfl_xor(s, off);
        if (tid == 0) sbase = s;
    }
    __syncthreads();
    int cs = sbase, cc = btot[b];
    const uint4* xq = (const uint4*)xphu;
    for (int i = tid; i < cc; i += 1024) {
        unsigned v = ebuf[cs + i];
        int dl = (int)(v >> 17), s = (int)(v & 0x1FFFFu);
        int r = atomicAdd(&lc[dl], 1);
        if (r < PAD) {
            col64[(size_t)(lo + dl) * PAD + r] = s;
        } else {
            int q = atomicAdd(ovcnt, 1);
            if (q < OVCAP) { ov[2 * q] = lo + dl; ov[2 * q + 1] = s; }
        }
        uint4 u0 = xq[s * 2], u1 = xq[s * 2 + 1];
        float* arow = &ash[dl * 17];
        float2 f;
        f = __half22float2(*(__half2*)&u0.x); atomicAdd(&arow[0], f.x); atomicAdd(&arow[1], f.y);
        f = __half22float2(*(__half2*)&u0.y); atomicAdd(&arow[2], f.x); atomicAdd(&arow[3], f.y);
        f = __half22float2(*(__half2*)&u0.z); atomicAdd(&arow[4], f.x); atomicAdd(&arow[5], f.y);
        f = __half22float2(*(__half2*)&u0.w); atomicAdd(&arow[6], f.x); atomicAdd(&arow[7], f.y);
        f = __half22float2(*(__half2*)&u1.x); atomicAdd(&arow[8], f.x); atomicAdd(&arow[9], f.y);
        f = __half22float2(*(__half2*)&u1.y); atomicAdd(&arow[10], f.x);   // ch 11..15 = 0
    }
    __syncthreads();
    int n = lo + tid;
    if (n < N) {
        int d = lc[tid];
        cnt[n] = d;
        int dc = min(d, PAD);
        int* row = col64 + (size_t)n * PAD;
        for (int r = dc; r < PAD; r++) row[r] = N;
    }
    #pragma unroll
    for (int j = 0; j < 16; j++) {      // agg1 out: 1024 nodes x 16 ch fp32
        int idx = tid + j * 1024;
        int nl = idx >> 4, ch = idx & 15;
        if (lo + nl < N) agg1[(size_t)(lo + nl) * 16 + ch] = ash[nl * 17 + ch];
    }
}

// ---------------- layer 1 dense: h1 = relu(Wl1*mean + Wr1*x + b) -> fp16 ------
__global__ void k_dense1(const float* __restrict__ x, const float* __restrict__ agg1,
                         const int* __restrict__ cnt, const float* __restrict__ Wl,
                         const float* __restrict__ bl, const float* __restrict__ Wr,
                         unsigned* __restrict__ h1h, int N) {
    int lane = threadIdx.x & 63;
    int n = blockIdx.x * 4 + (threadIdx.x >> 6);
    if (n > N) return;
    if (n == N) {
        if (lane < 32) h1h[n * 32 + lane] = 0u;
        return;
    }
    int deg = cnt[n];
    float inv = deg > 0 ? 1.f / (float)deg : 0.f;
    float mv = (lane < 16) ? agg1[n * 16 + lane] * inv : 0.f;
    float xv = (lane < IN_CH) ? x[n * IN_CH + lane] : 0.f;
    float h = bl[lane];
    #pragma unroll
    for (int c = 0; c < IN_CH; c++)
        h += Wl[lane * IN_CH + c] * __shfl(mv, c) + Wr[lane * IN_CH + c] * __shfl(xv, c);
    h = fmaxf(h, 0.f);
    unsigned my = (unsigned)__half_as_ushort(__float2half_rn(h));
    unsigned nx = __shfl_down(my, 1);
    if ((lane & 1) == 0) h1h[n * 32 + (lane >> 1)] = my | (nx << 16);
}

// ------- layer 2 aggregate: packed-fp16 accumulate, fp32 cross-lane reduce ----
// deg-aware: second 4-group batch only when deg > 32 (pads add exact +0)
__global__ void k_agg2(const uint4* __restrict__ h1h4, const int* __restrict__ col64,
                       const int* __restrict__ cnt, float* __restrict__ agg2, int N) {
    int lane = threadIdx.x & 63;
    int n = blockIdx.x * 4 + (threadIdx.x >> 6);
    if (n >= N) return;
    int c8 = lane & 7, sub = lane >> 3;
    const int* cb = col64 + n * PAD;
    int deg = cnt[n];
    __half2 a2[4];
    #pragma unroll
    for (int t = 0; t < 4; t++) a2[t] = __floats2half2_rn(0.f, 0.f);
    {
        int s[4];
        #pragma unroll
        for (int jj = 0; jj < 4; jj++) s[jj] = cb[sub + 8 * jj];
        uint4 v[4];
        #pragma unroll
        for (int jj = 0; jj < 4; jj++) v[jj] = h1h4[s[jj] * 8 + c8];
        #pragma unroll
        for (int jj = 0; jj < 4; jj++) {
            a2[0] = __hadd2(a2[0], *(__half2*)&v[jj].x);
            a2[1] = __hadd2(a2[1], *(__half2*)&v[jj].y);
            a2[2] = __hadd2(a2[2], *(__half2*)&v[jj].z);
            a2[3] = __hadd2(a2[3], *(__half2*)&v[jj].w);
        }
    }
    if (deg > 32) {
        int s[4];
        #pragma unroll
        for (int jj = 0; jj < 4; jj++) s[jj] = cb[sub + 8 * (4 + jj)];
        uint4 v[4];
        #pragma unroll
        for (int jj = 0; jj < 4; jj++) v[jj] = h1h4[s[jj] * 8 + c8];
        #pragma unroll
        for (int jj = 0; jj < 4; jj++) {
            a2[0] = __hadd2(a2[0], *(__half2*)&v[jj].x);
            a2[1] = __hadd2(a2[1], *(__half2*)&v[jj].y);
            a2[2] = __hadd2(a2[2], *(__half2*)&v[jj].z);
            a2[3] = __hadd2(a2[3], *(__half2*)&v[jj].w);
        }
    }
    float acc[8];
    #pragma unroll
    for (int t = 0; t < 4; t++) {
        float2 f = __half22float2(a2[t]);
        acc[2 * t] = f.x; acc[2 * t + 1] = f.y;
    }
    #pragma unroll
    for (int off = 8; off <= 32; off <<= 1) {
        #pragma unroll
        for (int t = 0; t < 8; t++) acc[t] += __shfl_xor(acc[t], off);
    }
    float val = acc[0];                        // channel = 8*c8 + sub
    #pragma unroll
    for (int t = 1; t < 8; t++) if (sub == t) val = acc[t];
    agg2[n * 64 + 8 * c8 + sub] = val;
}

__global__ void k_ov2(const int* __restrict__ ovcnt, const int* __restrict__ ov,
                      const unsigned* __restrict__ h1h, float* __restrict__ agg2) {
    int c = *ovcnt; if (c > OVCAP) c = OVCAP;
    const __half* h1 = (const __half*)h1h;
    for (int i = blockIdx.x * blockDim.x + threadIdx.x; i < c;
         i += gridDim.x * blockDim.x) {
        int d = ov[2 * i], s = ov[2 * i + 1];
        for (int ch = 0; ch < HID; ch++)
            atomicAdd(&agg2[d * 64 + ch], __half2float(h1[s * 64 + ch]));
    }
}

// ---- layer 2 dense as MFMA GEMM; mean division folded into A-fragment build
__global__ __launch_bounds__(256) void k_dense2(
    const float4* __restrict__ agg2_4, const int* __restrict__ cnt,
    const uint4* __restrict__ h1h_u4,
    const __half* __restrict__ wl2h, const __half* __restrict__ wr2h,
    const float* __restrict__ bl, const float* __restrict__ Wlin,
    const float* __restrict__ blin, float* __restrict__ out, int N) {
    union U { uint4 u; half8_t h; };
    int lane = threadIdx.x & 63;
    int wave = blockIdx.x * 4 + (threadIdx.x >> 6);
    int nwaves = gridDim.x * 4;
    int r16 = lane & 15, quad = lane >> 4;
    const uint4* wlu = (const uint4*)wl2h;
    const uint4* wru = (const uint4*)wr2h;
    half8_t bfr[4][4];
    #pragma unroll
    for (int tt = 0; tt < 4; tt++) {
        int o = tt * 16 + r16;
        U t0, t1, t2, t3;
        t0.u = wlu[o * 8 + quad];
        t1.u = wlu[o * 8 + 4 + quad];
        t2.u = wru[o * 8 + quad];
        t3.u = wru[o * 8 + 4 + quad];
        bfr[tt][0] = t0.h; bfr[tt][1] = t1.h; bfr[tt][2] = t2.h; bfr[tt][3] = t3.h;
    }
    float bl_c[4], wl_c[4];
    #pragma unroll
    for (int tt = 0; tt < 4; tt++) {
        bl_c[tt] = bl[tt * 16 + r16];
        wl_c[tt] = Wlin[tt * 16 + r16];
    }
    float b0 = blin[0];
    int ntiles = (N + 15) >> 4;
    for (int t = wave; t < ntiles; t += nwaves) {
        int nb = t * 16;
        int n = nb + r16; if (n >= N) n = N - 1;
        int deg = cnt[n];
        float inv = deg > 0 ? 1.f / (float)deg : 0.f;
        float4 m0 = agg2_4[n * 16 + quad * 2];
        float4 m1 = agg2_4[n * 16 + quad * 2 + 1];
        float4 m2 = agg2_4[n * 16 + 8 + quad * 2];
        float4 m3 = agg2_4[n * 16 + 8 + quad * 2 + 1];
        half8_t a0h, a1h;
        a0h[0] = (_Float16)(m0.x * inv); a0h[1] = (_Float16)(m0.y * inv);
        a0h[2] = (_Float16)(m0.z * inv); a0h[3] = (_Float16)(m0.w * inv);
        a0h[4] = (_Float16)(m1.x * inv); a0h[5] = (_Float16)(m1.y * inv);
        a0h[6] = (_Float16)(m1.z * inv); a0h[7] = (_Float16)(m1.w * inv);
        a1h[0] = (_Float16)(m2.x * inv); a1h[1] = (_Float16)(m2.y * inv);
        a1h[2] = (_Float16)(m2.z * inv); a1h[3] = (_Float16)(m2.w * inv);
        a1h[4] = (_Float16)(m3.x * inv); a1h[5] = (_Float16)(m3.y * inv);
        a1h[6] = (_Float16)(m3.z * inv); a1h[7] = (_Float16)(m3.w * inv);
        U a2, a3;
        a2.u = h1h_u4[n * 8 + quad];
        a3.u = h1h_u4[n * 8 + 4 + quad];
        float p0 = 0.f, p1 = 0.f, p2 = 0.f, p3 = 0.f;
        #pragma unroll
        for (int tt = 0; tt < 4; tt++) {
            f32x4_t c = {0.f, 0.f, 0.f, 0.f};
            c = __builtin_amdgcn_mfma_f32_16x16x32_f16(a0h, bfr[tt][0], c, 0, 0, 0);
            c = __builtin_amdgcn_mfma_f32_16x16x32_f16(a1h, bfr[tt][1], c, 0, 0, 0);
            c = __builtin_amdgcn_mfma_f32_16x16x32_f16(a2.h, bfr[tt][2], c, 0, 0, 0);
            c = __builtin_amdgcn_mfma_f32_16x16x32_f16(a3.h, bfr[tt][3], c, 0, 0, 0);
            p0 += fmaxf(c[0] + bl_c[tt], 0.f) * wl_c[tt];
            p1 += fmaxf(c[1] + bl_c[tt], 0.f) * wl_c[tt];
            p2 += fmaxf(c[2] + bl_c[tt], 0.f) * wl_c[tt];
            p3 += fmaxf(c[3] + bl_c[tt], 0.f) * wl_c[tt];
        }
        #pragma unroll
        for (int off = 1; off <= 8; off <<= 1) {
            p0 += __shfl_xor(p0, off); p1 += __shfl_xor(p1, off);
            p2 += __shfl_xor(p2, off); p3 += __shfl_xor(p3, off);
        }
        if (r16 == 0) {
            int nn = nb + quad * 4;
            if (nn + 3 < N) {
                ((float4*)out)[nn >> 2] = make_float4(p0 + b0, p1 + b0, p2 + b0, p3 + b0);
            } else {
                if (nn + 0 < N) out[nn + 0] = p0 + b0;
                if (nn + 1 < N) out[nn + 1] = p1 + b0;
                if (nn + 2 < N) out[nn + 2] = p2 + b0;
                if (nn + 3 < N) out[nn + 3] = p3 + b0;
            }
        }
    }
}

// ---------------- launch ----------------

extern "C" void kernel_launch(void* const* d_in, const int* in_sizes, int n_in,
                              void* d_out, int out_size, void* d_ws, size_t ws_size,
                              hipStream_t stream) {
    const float* x    = (const float*)d_in[0];
    const int*   ei   = (const int*)d_in[1];
    const float* Wl1  = (const float*)d_in[2];
    const float* bl1  = (const float*)d_in[3];
    const float* Wr1  = (const float*)d_in[4];
    const float* Wl2  = (const float*)d_in[5];
    const float* bl2  = (const float*)d_in[6];
    const float* Wr2  = (const float*)d_in[7];
    const float* Wlin = (const float*)d_in[8];
    const float* blin = (const float*)d_in[9];
    float* out = (float*)d_out;

    int N = in_sizes[0] / IN_CH;   // 100000
    int E = in_sizes[1] / 2;       // 3200000
    const int* srcp = ei;
    const int* dstp = ei + E;

    // workspace (int offsets; total 16,138,016 ints = 64.55 MB):
    //  cnt   @ 0          (N+1; ovcnt = cnt[N])
    //  col64 @ 100,032    (6.4M; bbuild->agg2) — hist overlays head (50,176)
    //  xph   @ 6,500,032  ((N+1)*8; prephist->bbuild)
    //  ebuf  @ 7,300,064  (3.2M; scatter->bbuild)
    //  agg1  @ 10,500,064 (1.6M; bbuild->dense1) — own region (bbuild uses both)
    //  agg2  @ 6,500,032  (6.4M; agg2->dense2; overlays dead xph/ebuf/agg1)
    //  h1h   @ 12,900,096 ((N+1)*32; dense1->dense2)
    //  ov    @ 16,100,128 (2*OVCAP)
    //  wl2h  @ 16,132,896 / wr2h @ 16,134,944 (2048 each)
    //  btot  @ 16,136,992 (1024)
    int* ws        = (int*)d_ws;
    int* cnt       = ws;
    int* ovcnt     = ws + N;
    int* col64     = ws + 100032;
    int* hist      = ws + 100032;
    unsigned* xph  = (unsigned*)(ws + 6500032);
    unsigned* ebuf = (unsigned*)(ws + 7300064);
    float* agg1    = (float*)(ws + 10500064);
    float* agg2    = (float*)(ws + 6500032);
    unsigned* h1h  = (unsigned*)(ws + 12900096);
    int* ov        = ws + 16100128;
    __half* wl2h   = (__half*)(ws + 16132896);
    __half* wr2h   = (__half*)(ws + 16134944);
    int* btot      = ws + 16136992;

    int nbkt = (N + 1023) >> BSH;         // 98
    int csz  = (E + NBLK - 1) / NBLK;     // 6250
    int prep_blocks = ((N + 1) * 8 + 255) / 256;   // 3126

    k_prephist<<<NBLK + prep_blocks, 256, 0, stream>>>(x, Wl2, Wr2, dstp, xph,
                                                       wl2h, wr2h, hist, ovcnt,
                                                       E, csz, nbkt, N);
    k_scanA  <<<nbkt, NBLK, 0, stream>>>(hist, btot);
    k_scatter<<<NBLK, 256, 0, stream>>>(srcp, dstp, hist, btot, ebuf, E, csz, nbkt);
    k_bbuild <<<nbkt, 1024, 0, stream>>>(ebuf, btot, xph, cnt, col64, agg1,
                                         ovcnt, ov, N);

    k_dense1 <<<(N + 4) / 4, 256, 0, stream>>>(x, agg1, cnt, Wl1, bl1, Wr1, h1h, N);

    k_agg2   <<<(N + 3) / 4, 256, 0, stream>>>((const uint4*)h1h, col64, cnt,
                                               agg2, N);
    k_ov2    <<<8, 256, 0, stream>>>(ovcnt, ov, h1h, agg2);

    k_dense2 <<<512, 256, 0, stream>>>((const float4*)agg2, cnt, (const uint4*)h1h,
                                       wl2h, wr2h, bl2, Wlin, blin, out, N);
}

// Round 14
// 287.248 us; speedup vs baseline: 2.4114x; 2.4114x over previous
//
#include <hip/hip_runtime.h>
#include <hip/hip_fp16.h>

#define IN_CH 11
#define HID 64
#define PAD 64
#define OVCAP 16384
#define NBLK 512
#define BSH 10           // super-bucket = dst >> 10 (1024 nodes)

typedef _Float16 half8_t __attribute__((ext_vector_type(8)));
typedef float f32x4_t __attribute__((ext_vector_type(4)));

// ---- fused prep + hist: role-split by blockIdx ----
// blocks [0,NBLK): per-chunk LDS histogram of dst>>BSH
// blocks [NBLK,..): x -> fp16 padded copy (stride 16, row N = 0), weights->fp16
__global__ __launch_bounds__(256) void k_prephist(
        const float* __restrict__ x, const float* __restrict__ Wl2,
        const float* __restrict__ Wr2, const int* __restrict__ dst,
        unsigned* __restrict__ xphu, __half* __restrict__ wl2h,
        __half* __restrict__ wr2h, int* __restrict__ hist,
        int* __restrict__ ovcnt, int E, int csz, int nbkt, int N) {
    __shared__ int h[128];
    int tid = threadIdx.x;
    if (blockIdx.x < NBLK) {
        int blk = blockIdx.x;
        if (tid < 128) h[tid] = 0;
        __syncthreads();
        int c0 = blk * csz, c1 = min(c0 + csz, E);
        for (int e = c0 + tid; e < c1; e += 256)
            atomicAdd(&h[dst[e] >> BSH], 1);
        __syncthreads();
        if (tid < nbkt) hist[tid * NBLK + blk] = h[tid];
    } else {
        int i = (blockIdx.x - NBLK) * 256 + tid;
        if (i == 0) *ovcnt = 0;
        if (i < HID * HID) {
            wl2h[i] = __float2half_rn(Wl2[i]);
            wr2h[i] = __float2half_rn(Wr2[i]);
        }
        if (i < (N + 1) * 8) {               // one uint = 2 fp16 channels
            int n = i >> 3, j = (i & 7) * 2;
            float a = 0.f, b = 0.f;
            if (n < N) {
                if (j < IN_CH) a = x[n * IN_CH + j];
                if (j + 1 < IN_CH) b = x[n * IN_CH + j + 1];
            }
            unsigned lo = (unsigned)__half_as_ushort(__float2half_rn(a));
            unsigned hi = (unsigned)__half_as_ushort(__float2half_rn(b));
            xphu[i] = lo | (hi << 16);
        }
    }
}

// per-bucket exclusive scan of its NBLK chunk counts (in place) + bucket total
__global__ __launch_bounds__(512) void k_scanA(int* __restrict__ hist,
        int* __restrict__ btot) {
    __shared__ int wsum[8];
    int b = blockIdx.x, tid = threadIdx.x;
    int lane = tid & 63, wv = tid >> 6;
    int v = hist[b * NBLK + tid];
    int inc = v;
    #pragma unroll
    for (int off = 1; off < 64; off <<= 1) {
        int t = __shfl_up(inc, off);
        if (lane >= off) inc += t;
    }
    if (lane == 63) wsum[wv] = inc;
    __syncthreads();
    int base = 0;
    #pragma unroll
    for (int w = 0; w < 8; w++) base += (w < wv) ? wsum[w] : 0;
    hist[b * NBLK + tid] = base + inc - v;
    if (tid == NBLK - 1) btot[b] = base + inc;
}

// scatter packed (dlocal<<17|src) into bucket-grouped ebuf via LDS cursors;
// bstart computed inline by a 2-wave shuffle scan of btot (nbkt <= 128)
__global__ __launch_bounds__(256) void k_scatter(const int* __restrict__ src,
        const int* __restrict__ dst, const int* __restrict__ hist,
        const int* __restrict__ btot,
        unsigned* __restrict__ ebuf, int E, int csz, int nbkt) {
    __shared__ int cur[128];
    __shared__ int wtmp;
    int tid = threadIdx.x, blk = blockIdx.x;
    int v = 0, inc = 0;
    if (tid < 128) {
        int lane = tid & 63;
        v = (tid < nbkt) ? btot[tid] : 0;
        inc = v;
        #pragma unroll
        for (int off = 1; off < 64; off <<= 1) {
            int t = __shfl_up(inc, off);
            if (lane >= off) inc += t;
        }
        if (tid == 63) wtmp = inc;
    }
    __syncthreads();
    if (tid < 128) {
        int base = (tid >= 64) ? wtmp : 0;
        int bs = base + inc - v;            // exclusive bstart[tid]
        cur[tid] = ((tid < nbkt) ? hist[tid * NBLK + blk] : 0) + bs;
    }
    __syncthreads();
    int c0 = blk * csz, c1 = min(c0 + csz, E);
    for (int e = c0 + tid; e < c1; e += 256) {
        int d = dst[e], s = src[e];
        int slot = atomicAdd(&cur[d >> BSH], 1);
        ebuf[slot] = ((unsigned)(d & 1023) << 17) | (unsigned)s;
    }
}

// one block per super-bucket: read its contiguous edges ONCE, rank via 4 KB
// LDS counters, write col64 directly (own 256 KB L2-resident region), fill
// pads in-kernel, write cnt. bstart computed inline (wave reduce of btot).
__global__ __launch_bounds__(1024) void k_bbuild(const unsigned* __restrict__ ebuf,
        const int* __restrict__ btot,
        int* __restrict__ cnt, int* __restrict__ col64,
        int* __restrict__ ovcnt, int* __restrict__ ov, int N) {
    __shared__ int lc[1024];
    __shared__ int sbase;
    int tid = threadIdx.x, b = blockIdx.x;
    int lo = b << BSH;
    lc[tid] = 0;
    if (tid < 64) {                     // bstart[b] = sum btot[0..b-1]
        int s = 0;
        for (int t = tid; t < b; t += 64) s += btot[t];
        #pragma unroll
        for (int off = 32; off >= 1; off >>= 1) s += __shfl_xor(s, off);
        if (tid == 0) sbase = s;
    }
    __syncthreads();
    int cs = sbase, cc = btot[b];
    for (int i = tid; i < cc; i += 1024) {
        unsigned v = ebuf[cs + i];
        int dl = (int)(v >> 17), s = (int)(v & 0x1FFFFu);
        int r = atomicAdd(&lc[dl], 1);
        if (r < PAD) {
            col64[(size_t)(lo + dl) * PAD + r] = s;
        } else {
            int q = atomicAdd(ovcnt, 1);
            if (q < OVCAP) { ov[2 * q] = lo + dl; ov[2 * q + 1] = s; }
        }
    }
    __syncthreads();
    int n = lo + tid;
    if (n < N) {
        int d = lc[tid];
        cnt[n] = d;
        int dc = min(d, PAD);
        int* row = col64 + (size_t)n * PAD;
        for (int r = dc; r < PAD; r++) row[r] = N;
    }
}

// ---- layer 1 aggregate: fp16 gather, packed adds; deg-aware half-batch trim
__global__ void k_agg1(const unsigned* __restrict__ xphu,
                       const int* __restrict__ col64, const int* __restrict__ cnt,
                       float* __restrict__ agg1, int N) {
    int lane = threadIdx.x & 63;
    int n = blockIdx.x * 4 + (threadIdx.x >> 6);
    if (n >= N) return;
    int c8 = lane & 7, sub = lane >> 3;      // 8 row slots x 8 uint lanes
    const int* cb = col64 + n * PAD;
    int deg = cnt[n];
    __half2 a2 = __floats2half2_rn(0.f, 0.f);
    {
        int s[4];
        #pragma unroll
        for (int jj = 0; jj < 4; jj++) s[jj] = cb[sub + 8 * jj];
        unsigned v[4];
        #pragma unroll
        for (int jj = 0; jj < 4; jj++) v[jj] = xphu[s[jj] * 8 + c8];
        #pragma unroll
        for (int jj = 0; jj < 4; jj++) a2 = __hadd2(a2, *(__half2*)&v[jj]);
    }
    if (deg > 32) {
        int s[4];
        #pragma unroll
        for (int jj = 0; jj < 4; jj++) s[jj] = cb[sub + 8 * (4 + jj)];
        unsigned v[4];
        #pragma unroll
        for (int jj = 0; jj < 4; jj++) v[jj] = xphu[s[jj] * 8 + c8];
        #pragma unroll
        for (int jj = 0; jj < 4; jj++) a2 = __hadd2(a2, *(__half2*)&v[jj]);
    }
    float2 f = __half22float2(a2);
    #pragma unroll
    for (int off = 8; off <= 32; off <<= 1) {
        f.x += __shfl_xor(f.x, off);
        f.y += __shfl_xor(f.y, off);
    }
    if (lane < 8) ((float2*)agg1)[n * 8 + lane] = f;   // channels 2*lane,2*lane+1
}

__global__ void k_ov1(const int* __restrict__ ovcnt, const int* __restrict__ ov,
                      const float* __restrict__ x, float* __restrict__ agg1) {
    int c = *ovcnt; if (c > OVCAP) c = OVCAP;
    for (int i = blockIdx.x * blockDim.x + threadIdx.x; i < c;
         i += gridDim.x * blockDim.x) {
        int d = ov[2 * i], s = ov[2 * i + 1];
        for (int ch = 0; ch < IN_CH; ch++)
            atomicAdd(&agg1[d * 16 + ch], x[s * IN_CH + ch]);
    }
}

// ---------------- layer 1 dense: h1 = relu(Wl1*mean + Wr1*x + b) -> fp16 ------
__global__ void k_dense1(const float* __restrict__ x, const float* __restrict__ agg1,
                         const int* __restrict__ cnt, const float* __restrict__ Wl,
                         const float* __restrict__ bl, const float* __restrict__ Wr,
                         unsigned* __restrict__ h1h, int N) {
    int lane = threadIdx.x & 63;
    int n = blockIdx.x * 4 + (threadIdx.x >> 6);
    if (n > N) return;
    if (n == N) {
        if (lane < 32) h1h[n * 32 + lane] = 0u;
        return;
    }
    int deg = cnt[n];
    float inv = deg > 0 ? 1.f / (float)deg : 0.f;
    float mv = (lane < 16) ? agg1[n * 16 + lane] * inv : 0.f;
    float xv = (lane < IN_CH) ? x[n * IN_CH + lane] : 0.f;
    float h = bl[lane];
    #pragma unroll
    for (int c = 0; c < IN_CH; c++)
        h += Wl[lane * IN_CH + c] * __shfl(mv, c) + Wr[lane * IN_CH + c] * __shfl(xv, c);
    h = fmaxf(h, 0.f);
    unsigned my = (unsigned)__half_as_ushort(__float2half_rn(h));
    unsigned nx = __shfl_down(my, 1);
    if ((lane & 1) == 0) h1h[n * 32 + (lane >> 1)] = my | (nx << 16);
}

// ------- layer 2 aggregate: packed-fp16 accumulate, fp32 cross-lane reduce ----
// deg-aware: second 4-group batch only when deg > 32 (pads add exact +0)
__global__ void k_agg2(const uint4* __restrict__ h1h4, const int* __restrict__ col64,
                       const int* __restrict__ cnt, float* __restrict__ agg2, int N) {
    int lane = threadIdx.x & 63;
    int n = blockIdx.x * 4 + (threadIdx.x >> 6);
    if (n >= N) return;
    int c8 = lane & 7, sub = lane >> 3;
    const int* cb = col64 + n * PAD;
    int deg = cnt[n];
    __half2 a2[4];
    #pragma unroll
    for (int t = 0; t < 4; t++) a2[t] = __floats2half2_rn(0.f, 0.f);
    {
        int s[4];
        #pragma unroll
        for (int jj = 0; jj < 4; jj++) s[jj] = cb[sub + 8 * jj];
        uint4 v[4];
        #pragma unroll
        for (int jj = 0; jj < 4; jj++) v[jj] = h1h4[s[jj] * 8 + c8];
        #pragma unroll
        for (int jj = 0; jj < 4; jj++) {
            a2[0] = __hadd2(a2[0], *(__half2*)&v[jj].x);
            a2[1] = __hadd2(a2[1], *(__half2*)&v[jj].y);
            a2[2] = __hadd2(a2[2], *(__half2*)&v[jj].z);
            a2[3] = __hadd2(a2[3], *(__half2*)&v[jj].w);
        }
    }
    if (deg > 32) {
        int s[4];
        #pragma unroll
        for (int jj = 0; jj < 4; jj++) s[jj] = cb[sub + 8 * (4 + jj)];
        uint4 v[4];
        #pragma unroll
        for (int jj = 0; jj < 4; jj++) v[jj] = h1h4[s[jj] * 8 + c8];
        #pragma unroll
        for (int jj = 0; jj < 4; jj++) {
            a2[0] = __hadd2(a2[0], *(__half2*)&v[jj].x);
            a2[1] = __hadd2(a2[1], *(__half2*)&v[jj].y);
            a2[2] = __hadd2(a2[2], *(__half2*)&v[jj].z);
            a2[3] = __hadd2(a2[3], *(__half2*)&v[jj].w);
        }
    }
    float acc[8];
    #pragma unroll
    for (int t = 0; t < 4; t++) {
        float2 f = __half22float2(a2[t]);
        acc[2 * t] = f.x; acc[2 * t + 1] = f.y;
    }
    #pragma unroll
    for (int off = 8; off <= 32; off <<= 1) {
        #pragma unroll
        for (int t = 0; t < 8; t++) acc[t] += __shfl_xor(acc[t], off);
    }
    float val = acc[0];                        // channel = 8*c8 + sub
    #pragma unroll
    for (int t = 1; t < 8; t++) if (sub == t) val = acc[t];
    agg2[n * 64 + 8 * c8 + sub] = val;
}

__global__ void k_ov2(const int* __restrict__ ovcnt, const int* __restrict__ ov,
                      const unsigned* __restrict__ h1h, float* __restrict__ agg2) {
    int c = *ovcnt; if (c > OVCAP) c = OVCAP;
    const __half* h1 = (const __half*)h1h;
    for (int i = blockIdx.x * blockDim.x + threadIdx.x; i < c;
         i += gridDim.x * blockDim.x) {
        int d = ov[2 * i], s = ov[2 * i + 1];
        for (int ch = 0; ch < HID; ch++)
            atomicAdd(&agg2[d * 64 + ch], __half2float(h1[s * 64 + ch]));
    }
}

// ---- layer 2 dense as MFMA GEMM; mean division folded into A-fragment build
__global__ __launch_bounds__(256) void k_dense2(
    const float4* __restrict__ agg2_4, const int* __restrict__ cnt,
    const uint4* __restrict__ h1h_u4,
    const __half* __restrict__ wl2h, const __half* __restrict__ wr2h,
    const float* __restrict__ bl, const float* __restrict__ Wlin,
    const float* __restrict__ blin, float* __restrict__ out, int N) {
    union U { uint4 u; half8_t h; };
    int lane = threadIdx.x & 63;
    int wave = blockIdx.x * 4 + (threadIdx.x >> 6);
    int nwaves = gridDim.x * 4;
    int r16 = lane & 15, quad = lane >> 4;
    const uint4* wlu = (const uint4*)wl2h;
    const uint4* wru = (const uint4*)wr2h;
    half8_t bfr[4][4];
    #pragma unroll
    for (int tt = 0; tt < 4; tt++) {
        int o = tt * 16 + r16;
        U t0, t1, t2, t3;
        t0.u = wlu[o * 8 + quad];
        t1.u = wlu[o * 8 + 4 + quad];
        t2.u = wru[o * 8 + quad];
        t3.u = wru[o * 8 + 4 + quad];
        bfr[tt][0] = t0.h; bfr[tt][1] = t1.h; bfr[tt][2] = t2.h; bfr[tt][3] = t3.h;
    }
    float bl_c[4], wl_c[4];
    #pragma unroll
    for (int tt = 0; tt < 4; tt++) {
        bl_c[tt] = bl[tt * 16 + r16];
        wl_c[tt] = Wlin[tt * 16 + r16];
    }
    float b0 = blin[0];
    int ntiles = (N + 15) >> 4;
    for (int t = wave; t < ntiles; t += nwaves) {
        int nb = t * 16;
        int n = nb + r16; if (n >= N) n = N - 1;
        int deg = cnt[n];
        float inv = deg > 0 ? 1.f / (float)deg : 0.f;
        float4 m0 = agg2_4[n * 16 + quad * 2];
        float4 m1 = agg2_4[n * 16 + quad * 2 + 1];
        float4 m2 = agg2_4[n * 16 + 8 + quad * 2];
        float4 m3 = agg2_4[n * 16 + 8 + quad * 2 + 1];
        half8_t a0h, a1h;
        a0h[0] = (_Float16)(m0.x * inv); a0h[1] = (_Float16)(m0.y * inv);
        a0h[2] = (_Float16)(m0.z * inv); a0h[3] = (_Float16)(m0.w * inv);
        a0h[4] = (_Float16)(m1.x * inv); a0h[5] = (_Float16)(m1.y * inv);
        a0h[6] = (_Float16)(m1.z * inv); a0h[7] = (_Float16)(m1.w * inv);
        a1h[0] = (_Float16)(m2.x * inv); a1h[1] = (_Float16)(m2.y * inv);
        a1h[2] = (_Float16)(m2.z * inv); a1h[3] = (_Float16)(m2.w * inv);
        a1h[4] = (_Float16)(m3.x * inv); a1h[5] = (_Float16)(m3.y * inv);
        a1h[6] = (_Float16)(m3.z * inv); a1h[7] = (_Float16)(m3.w * inv);
        U a2, a3;
        a2.u = h1h_u4[n * 8 + quad];
        a3.u = h1h_u4[n * 8 + 4 + quad];
        float p0 = 0.f, p1 = 0.f, p2 = 0.f, p3 = 0.f;
        #pragma unroll
        for (int tt = 0; tt < 4; tt++) {
            f32x4_t c = {0.f, 0.f, 0.f, 0.f};
            c = __builtin_amdgcn_mfma_f32_16x16x32_f16(a0h, bfr[tt][0], c, 0, 0, 0);
            c = __builtin_amdgcn_mfma_f32_16x16x32_f16(a1h, bfr[tt][1], c, 0, 0, 0);
            c = __builtin_amdgcn_mfma_f32_16x16x32_f16(a2.h, bfr[tt][2], c, 0, 0, 0);
            c = __builtin_amdgcn_mfma_f32_16x16x32_f16(a3.h, bfr[tt][3], c, 0, 0, 0);
            p0 += fmaxf(c[0] + bl_c[tt], 0.f) * wl_c[tt];
            p1 += fmaxf(c[1] + bl_c[tt], 0.f) * wl_c[tt];
            p2 += fmaxf(c[2] + bl_c[tt], 0.f) * wl_c[tt];
            p3 += fmaxf(c[3] + bl_c[tt], 0.f) * wl_c[tt];
        }
        #pragma unroll
        for (int off = 1; off <= 8; off <<= 1) {
            p0 += __shfl_xor(p0, off); p1 += __shfl_xor(p1, off);
            p2 += __shfl_xor(p2, off); p3 += __shfl_xor(p3, off);
        }
        if (r16 == 0) {
            int nn = nb + quad * 4;
            if (nn + 3 < N) {
                ((float4*)out)[nn >> 2] = make_float4(p0 + b0, p1 + b0, p2 + b0, p3 + b0);
            } else {
                if (nn + 0 < N) out[nn + 0] = p0 + b0;
                if (nn + 1 < N) out[nn + 1] = p1 + b0;
                if (nn + 2 < N) out[nn + 2] = p2 + b0;
                if (nn + 3 < N) out[nn + 3] = p3 + b0;
            }
        }
    }
}

// ---------------- launch ----------------

extern "C" void kernel_launch(void* const* d_in, const int* in_sizes, int n_in,
                              void* d_out, int out_size, void* d_ws, size_t ws_size,
                              hipStream_t stream) {
    const float* x    = (const float*)d_in[0];
    const int*   ei   = (const int*)d_in[1];
    const float* Wl1  = (const float*)d_in[2];
    const float* bl1  = (const float*)d_in[3];
    const float* Wr1  = (const float*)d_in[4];
    const float* Wl2  = (const float*)d_in[5];
    const float* bl2  = (const float*)d_in[6];
    const float* Wr2  = (const float*)d_in[7];
    const float* Wlin = (const float*)d_in[8];
    const float* blin = (const float*)d_in[9];
    float* out = (float*)d_out;

    int N = in_sizes[0] / IN_CH;   // 100000
    int E = in_sizes[1] / 2;       // 3200000
    const int* srcp = ei;
    const int* dstp = ei + E;

    // workspace (int offsets; ~64.6 MB):
    //  cnt   @ 0          (N+1; ovcnt = cnt[N])
    //  col64 @ 100,032    (6.4M; bbuild->agg2) — hist overlays head (50,176)
    //  xph   @ 6,500,032  ((N+1)*8; prephist->agg1)
    //  ebuf  @ 7,300,064  (3.2M; scatter->bbuild)
    //  agg1  @ 10,500,064 (1.6M; agg1->dense1)
    //  agg2  @ 6,500,032  (6.4M; agg2->dense2; overlays dead xph/ebuf/agg1)
    //  h1h   @ 12,900,096 ((N+1)*32; dense1->dense2)
    //  ov    @ 16,100,128 (2*OVCAP)
    //  wl2h  @ 16,132,896 / wr2h @ 16,134,944 (2048 each)
    //  btot  @ 16,136,992 (1024)
    int* ws        = (int*)d_ws;
    int* cnt       = ws;
    int* ovcnt     = ws + N;
    int* col64     = ws + 100032;
    int* hist      = ws + 100032;
    unsigned* xph  = (unsigned*)(ws + 6500032);
    unsigned* ebuf = (unsigned*)(ws + 7300064);
    float* agg1    = (float*)(ws + 10500064);
    float* agg2    = (float*)(ws + 6500032);
    unsigned* h1h  = (unsigned*)(ws + 12900096);
    int* ov        = ws + 16100128;
    __half* wl2h   = (__half*)(ws + 16132896);
    __half* wr2h   = (__half*)(ws + 16134944);
    int* btot      = ws + 16136992;

    int nbkt = (N + 1023) >> BSH;         // 98
    int csz  = (E + NBLK - 1) / NBLK;     // 6250
    int prep_blocks = ((N + 1) * 8 + 255) / 256;   // 3126

    k_prephist<<<NBLK + prep_blocks, 256, 0, stream>>>(x, Wl2, Wr2, dstp, xph,
                                                       wl2h, wr2h, hist, ovcnt,
                                                       E, csz, nbkt, N);
    k_scanA  <<<nbkt, NBLK, 0, stream>>>(hist, btot);
    k_scatter<<<NBLK, 256, 0, stream>>>(srcp, dstp, hist, btot, ebuf, E, csz, nbkt);
    k_bbuild <<<nbkt, 1024, 0, stream>>>(ebuf, btot, cnt, col64, ovcnt, ov, N);

    k_agg1   <<<(N + 3) / 4, 256, 0, stream>>>(xph, col64, cnt, agg1, N);
    k_ov1    <<<8, 256, 0, stream>>>(ovcnt, ov, x, agg1);
    k_dense1 <<<(N + 4) / 4, 256, 0, stream>>>(x, agg1, cnt, Wl1, bl1, Wr1, h1h, N);

    k_agg2   <<<(N + 3) / 4, 256, 0, stream>>>((const uint4*)h1h, col64, cnt,
                                               agg2, N);
    k_ov2    <<<8, 256, 0, stream>>>(ovcnt, ov, h1h, agg2);

    k_dense2 <<<512, 256, 0, stream>>>((const float4*)agg2, cnt, (const uint4*)h1h,
                                       wl2h, wr2h, bl2, Wlin, blin, out, N);
}